// Round 4
// baseline (3113.187 us; speedup 1.0000x reference)
//
#include <hip/hip_runtime.h>

typedef __bf16 bf16;
typedef __bf16 bf16x8 __attribute__((ext_vector_type(8)));
typedef float f32x4 __attribute__((ext_vector_type(4)));
typedef unsigned int u32x4 __attribute__((ext_vector_type(4)));

#define T_STEPS 256

__device__ __forceinline__ float fast_sigmoid(float v) {
    return __fdividef(1.0f, 1.0f + __expf(-v));
}
__device__ __forceinline__ float fast_tanh(float v) {
    v = fminf(fmaxf(v, -15.0f), 15.0f);
    float e2 = __expf(2.0f * v);
    return __fdividef(e2 - 1.0f, e2 + 1.0f);
}

// ---------------------------------------------------------------------------
// Init: x -> bf16 (one-time, off the recurrence chain), zero h buf 0, flags.
// ---------------------------------------------------------------------------
__global__ void init_kernel(const float* __restrict__ x, bf16* __restrict__ xb,
                            bf16* __restrict__ hb0, unsigned int* __restrict__ flags) {
    int gid = blockIdx.x * blockDim.x + threadIdx.x;   // 4,194,304 threads
    {   // one 8-element chunk per thread: 33,554,432 els total
        const float* src = x + (size_t)gid * 8;
        float4 v0 = *(const float4*)(src);
        float4 v1 = *(const float4*)(src + 4);
        bf16x8 f;
        f[0]=(bf16)v0.x; f[1]=(bf16)v0.y; f[2]=(bf16)v0.z; f[3]=(bf16)v0.w;
        f[4]=(bf16)v1.x; f[5]=(bf16)v1.y; f[6]=(bf16)v1.z; f[7]=(bf16)v1.w;
        *(bf16x8*)(xb + (size_t)gid * 8) = f;
    }
    if (gid < 16384) *(u32x4*)(hb0 + gid * 8) = (u32x4){0u, 0u, 0u, 0u};
    if (gid < 4096)  flags[gid] = 0u;
}

// ---------------------------------------------------------------------------
// Persistent LSTM v5: 256 WGs x 512 thr, grid == CUs, 1 WG/CU.
// Group grp = bid&7 owns batch rows [16grp,+16); member s = bid>>3 owns
// h-cols [32s,+32) x 4 gates. Each WG's 8 waves cover the FULL K=2048:
// wave w handles x-k [128w,+128) AND h-k [1024+128w,+128), so the z-combine
// is WG-local (LDS) and the inter-WG barrier is 32 WGs (vs 64 in v1).
// Per step per wave: issue x loads -> poll group flags -> issue h loads ->
// vmcnt(4) -> 32 x-MFMAs (hide h RTT) -> vmcnt(0) -> 32 h-MFMAs.
// Handoff protocol: EXACTLY v1's proven semantics (single flag per WG,
// posted by tid0 after s3; consumers poll all 32 group flags; h double
// buffer lap-safe by the transitive argument). System scope (sc0 sc1)
// everywhere -- no placement assumptions (G16).
// ---------------------------------------------------------------------------
__global__ __launch_bounds__(512, 1) void lstm_persist(
    const bf16* __restrict__ xb,
    const float* __restrict__ Wf, const float* __restrict__ bfp,
    const float* __restrict__ Wi, const float* __restrict__ bip,
    const float* __restrict__ Wg, const float* __restrict__ bgp,
    const float* __restrict__ Wo, const float* __restrict__ bop,
    bf16* __restrict__ hb, unsigned int* __restrict__ flags)
{
    __shared__ float zb[8][16][132];   // 67.6 KB: per-wave partials [16 rows][4g*32cols+pad]

    const int bid  = blockIdx.x;
    const int grp  = bid & 7;          // batch rows [16grp, +16)
    const int s    = bid >> 3;         // h-col block [32s, +32) per gate
    const int tid  = threadIdx.x;
    const int lane = tid & 63;
    const int w    = tid >> 6;         // k slice [128w,+128) in each of x/h parts
    const int l16  = lane & 15;
    const int l4   = lane >> 4;

    // ---- persistent B fragments: [gate][cf][part(x=0,h=1)][ks]
    //      n = 32s + 16cf + l16 ; k = part*1024 + 128w + 32ks + 8*l4
    const float* Wptr[4] = {Wf, Wi, Wg, Wo};
    bf16x8 bfrag[4][2][2][4];          // 64 frags = 256 VGPR
    #pragma unroll
    for (int g = 0; g < 4; ++g)
        #pragma unroll
        for (int cf = 0; cf < 2; ++cf) {
            const float* wr0 = Wptr[g] + (size_t)(s * 32 + cf * 16 + l16) * 2048 + w * 128 + l4 * 8;
            #pragma unroll
            for (int part = 0; part < 2; ++part)
                #pragma unroll
                for (int ks = 0; ks < 4; ++ks) {
                    const float* wr = wr0 + part * 1024 + ks * 32;
                    float4 a = *(const float4*)(wr);
                    float4 b = *(const float4*)(wr + 4);
                    bf16x8 f;
                    f[0]=(bf16)a.x; f[1]=(bf16)a.y; f[2]=(bf16)a.z; f[3]=(bf16)a.w;
                    f[4]=(bf16)b.x; f[5]=(bf16)b.y; f[6]=(bf16)b.z; f[7]=(bf16)b.w;
                    bfrag[g][cf][part][ks] = f;
                }
        }

    // ---- combine ownership: tid<256 -> (row crow_l = tid>>4, cols 2cp,2cp+1)
    const int crow_l = tid >> 4;       // 0..15
    const int cp     = tid & 15;       // col pair within [0,32)
    const float* Bptr[4] = {bfp, bip, bgp, bop};
    float bias_[4][2];
    if (tid < 256) {
        #pragma unroll
        for (int g = 0; g < 4; ++g)
            #pragma unroll
            for (int j = 0; j < 2; ++j)
                bias_[g][j] = Bptr[g][s * 32 + 2 * cp + j];
    }
    float creg0 = 0.0f, creg1 = 0.0f;

    const bf16* xrow0 = xb + (size_t)(16 * grp + l16) * 1024 + w * 128 + l4 * 8;
    const bf16* hrow  = hb + (size_t)(16 * grp + l16) * 1024 + w * 128 + l4 * 8;
    unsigned int* const myflag = flags + (grp * 32 + s) * 16;
    const unsigned int* const fl = flags + (grp * 32 + (lane & 31)) * 16;
    unsigned int* const hdst0 = (unsigned int*)(hb + (size_t)(16 * grp + crow_l) * 1024
                                                + s * 32 + 2 * cp);

    for (int t = 0; t < T_STEPS; ++t) {
        const int p = t & 1;
        // ---- issue x A-frag loads (read-only, always available) ----
        const bf16* xrow = xrow0 + (size_t)t * 131072;
        u32x4 xv[4];
        #pragma unroll
        for (int ks = 0; ks < 4; ++ks)
            asm volatile("global_load_dwordx4 %0, %1, off"
                         : "=v"(xv[ks]) : "v"((const void*)(xrow + ks * 32)));
        // ---- poll all 32 producers of this group (v1 semantics) ----
        if (t > 0) {
            unsigned fv;
            do {
                asm volatile("global_load_dword %0, %1, off sc0 sc1\n\ts_waitcnt vmcnt(0)"
                             : "=v"(fv) : "v"((const void*)fl) : "memory");
            } while (__any((int)(fv < (unsigned)t)));
        }
        // ---- issue h A-frag loads (system scope) ----
        const bf16* hbase = hrow + p * 131072;
        u32x4 hv[4];
        #pragma unroll
        for (int ks = 0; ks < 4; ++ks)
            asm volatile("global_load_dwordx4 %0, %1, off sc0 sc1"
                         : "=v"(hv[ks]) : "v"((const void*)(hbase + ks * 32)));

        f32x4 acc[4][2];
        #pragma unroll
        for (int g = 0; g < 4; ++g)
            #pragma unroll
            for (int cf = 0; cf < 2; ++cf) acc[g][cf] = (f32x4){0.f, 0.f, 0.f, 0.f};

        // ---- x GEMM while h loads are in flight ----
        asm volatile("s_waitcnt vmcnt(4)" ::: "memory");   // x landed (h still out)
        __builtin_amdgcn_sched_barrier(0);                 // rule #18 fence
        #pragma unroll
        for (int ks = 0; ks < 4; ++ks) {
            bf16x8 a = __builtin_bit_cast(bf16x8, xv[ks]);
            #pragma unroll
            for (int g = 0; g < 4; ++g)
                #pragma unroll
                for (int cf = 0; cf < 2; ++cf)
                    acc[g][cf] = __builtin_amdgcn_mfma_f32_16x16x32_bf16(
                        a, bfrag[g][cf][0][ks], acc[g][cf], 0, 0, 0);
        }
        // ---- h GEMM ----
        asm volatile("s_waitcnt vmcnt(0)" ::: "memory");   // h landed
        __builtin_amdgcn_sched_barrier(0);
        #pragma unroll
        for (int ks = 0; ks < 4; ++ks) {
            bf16x8 a = __builtin_bit_cast(bf16x8, hv[ks]);
            #pragma unroll
            for (int g = 0; g < 4; ++g)
                #pragma unroll
                for (int cf = 0; cf < 2; ++cf)
                    acc[g][cf] = __builtin_amdgcn_mfma_f32_16x16x32_bf16(
                        a, bfrag[g][cf][1][ks], acc[g][cf], 0, 0, 0);
        }

        // ---- partials -> LDS (per-instr 2-way bank alias = free) ----
        #pragma unroll
        for (int g = 0; g < 4; ++g)
            #pragma unroll
            for (int cf = 0; cf < 2; ++cf)
                #pragma unroll
                for (int r = 0; r < 4; ++r)
                    zb[w][l4 * 4 + r][g * 32 + cf * 16 + l16] = acc[g][cf][r];
        __syncthreads();   // s2: all 8 waves' partials visible

        // ---- combine (WG-local): sum 8 waves + bias, gates, packed store ----
        if (tid < 256) {
            float z[4][2];
            #pragma unroll
            for (int g = 0; g < 4; ++g) { z[g][0] = 0.f; z[g][1] = 0.f; }
            #pragma unroll
            for (int k = 0; k < 8; ++k)
                #pragma unroll
                for (int g = 0; g < 4; ++g) {
                    float2 v = *(const float2*)(&zb[k][crow_l][g * 32 + 2 * cp]);
                    z[g][0] += v.x; z[g][1] += v.y;
                }
            float hv2[2];
            #pragma unroll
            for (int j = 0; j < 2; ++j) {
                float ig = fast_sigmoid(z[0][j] + bias_[0][j]);
                float fg = fast_sigmoid(z[1][j] + bias_[1][j]);
                float gg = fast_tanh   (z[2][j] + bias_[2][j]);
                float og = fast_sigmoid(z[3][j] + bias_[3][j]);
                float& cr = j ? creg1 : creg0;
                cr = fg * cr + ig * gg;
                hv2[j] = og * fast_tanh(cr);
            }
            unsigned short u0 = __builtin_bit_cast(unsigned short, (bf16)hv2[0]);
            unsigned short u1 = __builtin_bit_cast(unsigned short, (bf16)hv2[1]);
            unsigned packed = ((unsigned)u1 << 16) | u0;
            unsigned int* dst = hdst0 + ((t + 1) & 1) * 65536;   // 131072 bf16 = 65536 u32
            asm volatile("global_store_dword %0, %1, off sc0 sc1"
                         :: "v"(dst), "v"(packed) : "memory");
            asm volatile("s_waitcnt vmcnt(0)" ::: "memory");     // stores acked at MALL
        }
        __syncthreads();   // s3: all 256 combine stores acked
        if (tid == 0) {    // plain system store -- no RMW anywhere in the loop
            unsigned nv = (unsigned)(t + 1);
            asm volatile("global_store_dword %0, %1, off sc0 sc1"
                         :: "v"(myflag), "v"(nv) : "memory");
        }
    }
}

// ---------------------------------------------------------------------------
// logits = h_T @ Wout^T + bout (Wout converted inline from f32).
// ---------------------------------------------------------------------------
__global__ __launch_bounds__(512) void final_gemm_kernel(
    const bf16* __restrict__ hfin, const float* __restrict__ Wout,
    const float* __restrict__ bout, float* __restrict__ logits) {
    __shared__ alignas(16) bf16 Slds[128 * 72];
    const int tid  = threadIdx.x;
    const int lane = tid & 63;
    const int wave = tid >> 6;
    const int l16  = lane & 15;
    const int l4   = lane >> 4;
    const int n0   = blockIdx.x * 16;
    f32x4 acc = (f32x4){0.f, 0.f, 0.f, 0.f};
    for (int k0 = 0; k0 < 1024; k0 += 64) {
        #pragma unroll
        for (int i = 0; i < 2; ++i) {
            int cidx = tid + i * 512;
            int row = cidx >> 3, c8 = cidx & 7;
            *(uint4*)(&Slds[row * 72 + c8 * 8]) =
                *(const uint4*)(hfin + row * 1024 + k0 + c8 * 8);
        }
        __syncthreads();
        #pragma unroll
        for (int kk = 0; kk < 64; kk += 32) {
            const float* wrow = Wout + (size_t)(n0 + l16) * 1024 + k0 + kk + l4 * 8;
            float4 w0 = *(const float4*)(wrow);
            float4 w1 = *(const float4*)(wrow + 4);
            bf16x8 bfrag;
            bfrag[0]=(bf16)w0.x; bfrag[1]=(bf16)w0.y; bfrag[2]=(bf16)w0.z; bfrag[3]=(bf16)w0.w;
            bfrag[4]=(bf16)w1.x; bfrag[5]=(bf16)w1.y; bfrag[6]=(bf16)w1.z; bfrag[7]=(bf16)w1.w;
            bf16x8 afrag = *(const bf16x8*)(&Slds[(wave * 16 + l16) * 72 + kk + l4 * 8]);
            acc = __builtin_amdgcn_mfma_f32_16x16x32_bf16(afrag, bfrag, acc, 0, 0, 0);
        }
        __syncthreads();
    }
    float bv = bout[n0 + l16];
    #pragma unroll
    for (int r = 0; r < 4; ++r) {
        int m = wave * 16 + l4 * 4 + r;
        logits[m * 1024 + n0 + l16] = acc[r] + bv;
    }
}

// ---------------------------------------------------------------------------
// Row-wise log_softmax over 1024 logits. Grid 128 (one WG per batch row).
// ---------------------------------------------------------------------------
__global__ __launch_bounds__(256) void logsoftmax_kernel(
    const float* __restrict__ logits, float* __restrict__ out) {
    int b = blockIdx.x, tid = threadIdx.x;
    int lane = tid & 63, wv = tid >> 6;
    __shared__ float red[4];
    float v[4];
    float mx = -1e30f;
    #pragma unroll
    for (int i = 0; i < 4; ++i) {
        v[i] = logits[b * 1024 + i * 256 + tid];
        mx = fmaxf(mx, v[i]);
    }
    #pragma unroll
    for (int off = 1; off < 64; off <<= 1) mx = fmaxf(mx, __shfl_xor(mx, off));
    if (lane == 0) red[wv] = mx;
    __syncthreads();
    mx = fmaxf(fmaxf(red[0], red[1]), fmaxf(red[2], red[3]));
    float s = 0.f;
    #pragma unroll
    for (int i = 0; i < 4; ++i) s += __expf(v[i] - mx);
    #pragma unroll
    for (int off = 1; off < 64; off <<= 1) s += __shfl_xor(s, off);
    __syncthreads();
    if (lane == 0) red[wv] = s;
    __syncthreads();
    s = red[0] + red[1] + red[2] + red[3];
    float lse = mx + __logf(s);
    #pragma unroll
    for (int i = 0; i < 4; ++i) out[b * 1024 + i * 256 + tid] = v[i] - lse;
}

extern "C" void kernel_launch(void* const* d_in, const int* in_sizes, int n_in,
                              void* d_out, int out_size, void* d_ws, size_t ws_size,
                              hipStream_t stream) {
    const float* x    = (const float*)d_in[0];
    const float* Wf   = (const float*)d_in[1];
    const float* bfv  = (const float*)d_in[2];
    const float* Wi   = (const float*)d_in[3];
    const float* biv  = (const float*)d_in[4];
    const float* Wg   = (const float*)d_in[5];
    const float* bgv  = (const float*)d_in[6];
    const float* Wo   = (const float*)d_in[7];
    const float* bov  = (const float*)d_in[8];
    const float* Wout = (const float*)d_in[9];
    const float* bout = (const float*)d_in[10];
    float* out = (float*)d_out;

    // ws layout (~68 MB, identical footprint to the proven v1)
    char* p = (char*)d_ws;
    bf16* xb      = (bf16*)p;  p += (size_t)T_STEPS * 131072 * 2;   // 67 MB bf16 x
    bf16* hbuf    = (bf16*)p;  p += (size_t)2 * 131072 * 2;         // h double-buffer
    float* logits = (float*)p; p += (size_t)131072 * 4;
    unsigned int* flags = (unsigned int*)p; p += 4096 * 4;          // 256 flags, 64B apart
    if (ws_size < (size_t)(p - (char*)d_ws)) return;

    init_kernel<<<16384, 256, 0, stream>>>(x, xb, hbuf, flags);
    lstm_persist<<<256, 512, 0, stream>>>(xb, Wf, bfv, Wi, biv, Wg, bgv, Wo, bov,
                                          hbuf, flags);
    // t=255 writes hbuf buffer 0
    final_gemm_kernel<<<64, 512, 0, stream>>>(hbuf, Wout, bout, logits);
    logsoftmax_kernel<<<128, 256, 0, stream>>>(logits, out);
}

// Round 6
// 1510.441 us; speedup vs baseline: 2.0611x; 2.0611x over previous
//
#include <hip/hip_runtime.h>

typedef __bf16 bf16;
typedef __bf16 bf16x8 __attribute__((ext_vector_type(8)));
typedef float f32x4 __attribute__((ext_vector_type(4)));
typedef unsigned int u32x4 __attribute__((ext_vector_type(4)));

#define T_STEPS 256
#define NWG 256

__device__ __forceinline__ float fast_sigmoid(float v) {
    return __fdividef(1.0f, 1.0f + __expf(-v));
}
__device__ __forceinline__ float fast_tanh(float v) {
    v = fminf(fmaxf(v, -15.0f), 15.0f);
    float e2 = __expf(2.0f * v);
    return __fdividef(e2 - 1.0f, e2 + 1.0f);
}

// ---------------------------------------------------------------------------
// Init: convert whole x tensor to bf16 (one-time, off the recurrence chain),
// zero h buffer parity 0 (blocked layout, first 65536 dwords), zero flags.
// ---------------------------------------------------------------------------
__global__ void init_kernel(const float* __restrict__ x, bf16* __restrict__ xb,
                            bf16* __restrict__ hb0, unsigned int* __restrict__ flags) {
    int gid = blockIdx.x * blockDim.x + threadIdx.x;   // 4,194,304 threads
    {   // one 8-element chunk per thread: 33,554,432 els total
        const float* src = x + (size_t)gid * 8;
        float4 v0 = *(const float4*)(src);
        float4 v1 = *(const float4*)(src + 4);
        bf16x8 f;
        f[0]=(bf16)v0.x; f[1]=(bf16)v0.y; f[2]=(bf16)v0.z; f[3]=(bf16)v0.w;
        f[4]=(bf16)v1.x; f[5]=(bf16)v1.y; f[6]=(bf16)v1.z; f[7]=(bf16)v1.w;
        *(bf16x8*)(xb + (size_t)gid * 8) = f;
    }
    if (gid < 16384) *(u32x4*)(hb0 + gid * 8) = (u32x4){0u, 0u, 0u, 0u};
    if (gid < 4096)  flags[gid] = 0u;
}

// ---------------------------------------------------------------------------
// Persistent LSTM v6 = round-0 v1 + BLOCKED h layout.
// h stored as h[p][mq][tile][row32][colpair8] (dword units): each WG's
// combine writes dword block_base + tid -> 1 KB contiguous, 16 FULL 64B
// lines (v1: 256 scattered dwords, 32 half-written lines shared between
// WGs -> partial-line merge + slow ack at MALL). Consumer wave hw reads
// tiles [16hw,+16) = 16 KB contiguous (addr = base + tileL*1KB + lane*16B),
// scatters into the SAME [32][264] LDS staging; A-frag reads unchanged.
// Everything else (waves, flags, barriers, combine math) is v1 verbatim.
// ---------------------------------------------------------------------------
__global__ __launch_bounds__(512, 2) void lstm_persist(
    const bf16* __restrict__ xb,
    const float* __restrict__ Wf, const float* __restrict__ bfp,
    const float* __restrict__ Wi, const float* __restrict__ bip,
    const float* __restrict__ Wg, const float* __restrict__ bgp,
    const float* __restrict__ Wo, const float* __restrict__ bop,
    bf16* __restrict__ hb, unsigned int* __restrict__ flags)
{
    __shared__ bf16 S[4 * 32 * 264];   // 66 KB: h staging, wave-private [32][264]
    __shared__ float zb[8 * 2112];     // 66 KB: 8 partial bufs [32][66]

    const int wg   = blockIdx.x;
    const int mq   = wg & 3;
    const int tile = wg >> 2;
    const int tid  = threadIdx.x;
    const int lane = tid & 63;
    const int w    = tid >> 6;         // wave: k slice [256w, 256w+256)
    const int l16  = lane & 15;
    const int l4   = lane >> 4;
    unsigned int* const hb32 = (unsigned int*)hb;   // blocked h, dword units

    // ---- persistent B fragments: gate g, ks: W[n=tile*16+l16][k=256w+ks*32+l4*8]
    const float* Wptr[4] = {Wf, Wi, Wg, Wo};
    bf16x8 bfrag[4][8];
    #pragma unroll
    for (int g = 0; g < 4; ++g) {
        const float* wrow = Wptr[g] + (size_t)(tile * 16 + l16) * 2048 + 256 * w + l4 * 8;
        #pragma unroll
        for (int ks = 0; ks < 8; ++ks) {
            float4 a = *(const float4*)(wrow + ks * 32);
            float4 b = *(const float4*)(wrow + ks * 32 + 4);
            bf16x8 f;
            f[0]=(bf16)a.x; f[1]=(bf16)a.y; f[2]=(bf16)a.z; f[3]=(bf16)a.w;
            f[4]=(bf16)b.x; f[5]=(bf16)b.y; f[6]=(bf16)b.z; f[7]=(bf16)b.w;
            bfrag[g][ks] = f;
        }
    }

    // ---- combine ownership: threads 0..255 -> (row cb, cols 2cp, 2cp+1)
    const int cb = tid >> 3;
    const int cp = tid & 7;
    float bias0[2], bias1[2], bias2[2], bias3[2];
    if (tid < 256) {
        #pragma unroll
        for (int j = 0; j < 2; ++j) {
            int col = tile * 16 + 2 * cp + j;
            bias0[j] = bfp[col];  // gate0 -> i_t (ref naming swap)
            bias1[j] = bip[col];  // gate1 -> f_t
            bias2[j] = bgp[col];  // gate2 -> g_t
            bias3[j] = bop[col];  // gate3 -> o_t
        }
    }
    float creg0 = 0.0f, creg1 = 0.0f;

    for (int t = 0; t < T_STEPS; ++t) {
        f32x4 acc[2][4];
        #pragma unroll
        for (int mt = 0; mt < 2; ++mt)
            #pragma unroll
            for (int g = 0; g < 4; ++g) acc[mt][g] = (f32x4){0.f, 0.f, 0.f, 0.f};

        if (w < 4) {
            // ---- x path: A-frags straight from cached xb; two halves cap regs
            const bf16* xrow = xb + (size_t)t * 131072 + (size_t)(mq * 32 + l16) * 1024
                               + 256 * w + l4 * 8;
            #pragma unroll
            for (int half = 0; half < 2; ++half) {
                bf16x8 af[4][2];
                #pragma unroll
                for (int ks = 0; ks < 4; ++ks)
                    #pragma unroll
                    for (int mt = 0; mt < 2; ++mt)
                        af[ks][mt] = *(const bf16x8*)(xrow + (half * 4 + ks) * 32
                                                      + (size_t)mt * 16 * 1024);
                #pragma unroll
                for (int ks = 0; ks < 4; ++ks)
                    #pragma unroll
                    for (int mt = 0; mt < 2; ++mt)
                        #pragma unroll
                        for (int g = 0; g < 4; ++g)
                            acc[mt][g] = __builtin_amdgcn_mfma_f32_16x16x32_bf16(
                                af[ks][mt], bfrag[g][half * 4 + ks], acc[mt][g], 0, 0, 0);
            }
        } else {
            const int hw = w - 4;
            bf16* Sw = S + hw * 32 * 264;
            // ---- poll per-producer flags: 64 lanes -> 64 distinct 64B lines
            if (t > 0) {
                const unsigned int* fl = flags + (mq * 64 + lane) * 16;
                unsigned int fv;
                do {
                    fv = __hip_atomic_load(fl, __ATOMIC_RELAXED, __HIP_MEMORY_SCOPE_SYSTEM);
                } while (__any((int)(fv < (unsigned int)t)));
            }
            // ---- stage own h window from BLOCKED layout: 16 KB contiguous.
            //      base = block (p, mq, tile=16hw); instr (half,i) covers tile
            //      tileL = half*8+i, lane reads dwords tileL*256 + lane*4.
            const unsigned int* hbase = hb32 + ((size_t)((t & 1) * 4 + mq) * 64 + hw * 16) * 256;
            #pragma unroll
            for (int half = 0; half < 2; ++half) {
                u32x4 tmp[8];
                #pragma unroll
                for (int i = 0; i < 8; ++i) {
                    const void* g = hbase + (size_t)(half * 8 + i) * 256 + lane * 4;
                    asm volatile("global_load_dwordx4 %0, %1, off sc0 sc1"
                                 : "=v"(tmp[i]) : "v"(g));
                }
                asm volatile("s_waitcnt vmcnt(0)" ::: "memory");
                // decode: row = lane>>1, hh = lane&1; S col chunk = tileL*2+hh
                #pragma unroll
                for (int i = 0; i < 8; ++i) {
                    int tileL = half * 8 + i;
                    *(u32x4*)(&Sw[(lane >> 1) * 264 + tileL * 16 + (lane & 1) * 8]) = tmp[i];
                }
            }
            // ---- A-frags from own LDS region (wave-private -> no syncthreads)
            #pragma unroll
            for (int ks = 0; ks < 8; ++ks) {
                bf16x8 af[2];
                #pragma unroll
                for (int mt = 0; mt < 2; ++mt)
                    af[mt] = *(const bf16x8*)(&Sw[(mt * 16 + l16) * 264 + (ks * 4 + l4) * 8]);
                #pragma unroll
                for (int mt = 0; mt < 2; ++mt)
                    #pragma unroll
                    for (int g = 0; g < 4; ++g)
                        acc[mt][g] = __builtin_amdgcn_mfma_f32_16x16x32_bf16(
                            af[mt], bfrag[g][ks], acc[mt][g], 0, 0, 0);
            }
        }

        // ---- write partial buf w (pitch 66: 2-way banks = free)
        {
            float* pb = zb + w * 2112;
            #pragma unroll
            for (int mt = 0; mt < 2; ++mt)
                #pragma unroll
                for (int g = 0; g < 4; ++g)
                    #pragma unroll
                    for (int r = 0; r < 4; ++r)
                        pb[(mt * 16 + l4 * 4 + r) * 66 + g * 16 + l16] = acc[mt][g][r];
        }
        __syncthreads();  // s2: all partials visible

        // ---- combine: sum 8 bufs + bias, gates, c-reg, packed blocked store
        if (tid < 256) {
            float z[4][2];
            #pragma unroll
            for (int g = 0; g < 4; ++g) {
                z[g][0] = 0.f; z[g][1] = 0.f;
            }
            #pragma unroll
            for (int k = 0; k < 8; ++k) {
                const float* pb = zb + k * 2112 + cb * 66;
                #pragma unroll
                for (int g = 0; g < 4; ++g) {
                    float2 v = *(const float2*)(pb + g * 16 + 2 * cp);
                    z[g][0] += v.x; z[g][1] += v.y;
                }
            }
            float hv[2];
            #pragma unroll
            for (int j = 0; j < 2; ++j) {
                float ig = fast_sigmoid(z[0][j] + bias0[j]);
                float fg = fast_sigmoid(z[1][j] + bias1[j]);
                float gg = fast_tanh   (z[2][j] + bias2[j]);
                float og = fast_sigmoid(z[3][j] + bias3[j]);
                float& cr = j ? creg1 : creg0;
                cr = fg * cr + ig * gg;
                hv[j] = og * fast_tanh(cr);
            }
            unsigned short u0 = __builtin_bit_cast(unsigned short, (bf16)hv[0]);
            unsigned short u1 = __builtin_bit_cast(unsigned short, (bf16)hv[1]);
            unsigned int packed = ((unsigned int)u1 << 16) | u0;
            // blocked store: dword = block(p1, mq, tile)*256 + tid -> WG writes
            // 1 KB contiguous = 16 full lines, no partial-line merge.
            unsigned int* dst = hb32 + ((size_t)(((t + 1) & 1) * 4 + mq) * 64 + tile) * 256 + tid;
            __hip_atomic_store(dst, packed, __ATOMIC_RELAXED, __HIP_MEMORY_SCOPE_SYSTEM);
            asm volatile("s_waitcnt vmcnt(0)" ::: "memory");  // acked at MALL
        }
        __syncthreads();  // s3: all 256 combine stores acked
        if (tid == 0)     // plain system store -- no RMW anywhere in the loop
            __hip_atomic_store(flags + (mq * 64 + tile) * 16, (unsigned int)(t + 1),
                               __ATOMIC_RELAXED, __HIP_MEMORY_SCOPE_SYSTEM);
    }
}

// ---------------------------------------------------------------------------
// logits = h_T @ Wout^T + bout. hfin is BLOCKED (parity 0):
// dword = (mq*64 + tile)*256 + row32*8 + hh*4 for cols [tile*16+hh*8, +8).
// ---------------------------------------------------------------------------
__global__ __launch_bounds__(512) void final_gemm_kernel(
    const bf16* __restrict__ hfin, const float* __restrict__ Wout,
    const float* __restrict__ bout, float* __restrict__ logits) {
    __shared__ alignas(16) bf16 Slds[128 * 72];
    const unsigned int* const h32 = (const unsigned int*)hfin;
    const int tid  = threadIdx.x;
    const int lane = tid & 63;
    const int wave = tid >> 6;
    const int l16  = lane & 15;
    const int l4   = lane >> 4;
    const int n0   = blockIdx.x * 16;
    f32x4 acc = (f32x4){0.f, 0.f, 0.f, 0.f};
    for (int k0 = 0; k0 < 1024; k0 += 64) {
        #pragma unroll
        for (int i = 0; i < 2; ++i) {
            int cidx = tid + i * 512;
            int row = cidx >> 3, c8 = cidx & 7;
            int colb = k0 + c8 * 8;                 // 8-aligned col base
            int mq2 = row >> 5, r32 = row & 31;
            int tl = colb >> 4, hh = (colb >> 3) & 1;
            const uint4* src = (const uint4*)(h32 + ((size_t)(mq2 * 64 + tl) * 256
                                                     + r32 * 8 + hh * 4));
            *(uint4*)(&Slds[row * 72 + c8 * 8]) = *src;
        }
        __syncthreads();
        #pragma unroll
        for (int kk = 0; kk < 64; kk += 32) {
            const float* wrow = Wout + (size_t)(n0 + l16) * 1024 + k0 + kk + l4 * 8;
            float4 w0 = *(const float4*)(wrow);
            float4 w1 = *(const float4*)(wrow + 4);
            bf16x8 bfrag;
            bfrag[0]=(bf16)w0.x; bfrag[1]=(bf16)w0.y; bfrag[2]=(bf16)w0.z; bfrag[3]=(bf16)w0.w;
            bfrag[4]=(bf16)w1.x; bfrag[5]=(bf16)w1.y; bfrag[6]=(bf16)w1.z; bfrag[7]=(bf16)w1.w;
            bf16x8 afrag = *(const bf16x8*)(&Slds[(wave * 16 + l16) * 72 + kk + l4 * 8]);
            acc = __builtin_amdgcn_mfma_f32_16x16x32_bf16(afrag, bfrag, acc, 0, 0, 0);
        }
        __syncthreads();
    }
    float bv = bout[n0 + l16];
    #pragma unroll
    for (int r = 0; r < 4; ++r) {
        int m = wave * 16 + l4 * 4 + r;
        logits[m * 1024 + n0 + l16] = acc[r] + bv;
    }
}

// ---------------------------------------------------------------------------
// Row-wise log_softmax over 1024 logits. Grid 128 (one WG per batch row).
// ---------------------------------------------------------------------------
__global__ __launch_bounds__(256) void logsoftmax_kernel(
    const float* __restrict__ logits, float* __restrict__ out) {
    int b = blockIdx.x, tid = threadIdx.x;
    int lane = tid & 63, wv = tid >> 6;
    __shared__ float red[4];
    float v[4];
    float mx = -1e30f;
    #pragma unroll
    for (int i = 0; i < 4; ++i) {
        v[i] = logits[b * 1024 + i * 256 + tid];
        mx = fmaxf(mx, v[i]);
    }
    #pragma unroll
    for (int off = 1; off < 64; off <<= 1) mx = fmaxf(mx, __shfl_xor(mx, off));
    if (lane == 0) red[wv] = mx;
    __syncthreads();
    mx = fmaxf(fmaxf(red[0], red[1]), fmaxf(red[2], red[3]));
    float s = 0.f;
    #pragma unroll
    for (int i = 0; i < 4; ++i) s += __expf(v[i] - mx);
    #pragma unroll
    for (int off = 1; off < 64; off <<= 1) s += __shfl_xor(s, off);
    __syncthreads();
    if (lane == 0) red[wv] = s;
    __syncthreads();
    s = red[0] + red[1] + red[2] + red[3];
    float lse = mx + __logf(s);
    #pragma unroll
    for (int i = 0; i < 4; ++i) out[b * 1024 + i * 256 + tid] = v[i] - lse;
}

extern "C" void kernel_launch(void* const* d_in, const int* in_sizes, int n_in,
                              void* d_out, int out_size, void* d_ws, size_t ws_size,
                              hipStream_t stream) {
    const float* x    = (const float*)d_in[0];
    const float* Wf   = (const float*)d_in[1];
    const float* bfv  = (const float*)d_in[2];
    const float* Wi   = (const float*)d_in[3];
    const float* biv  = (const float*)d_in[4];
    const float* Wg   = (const float*)d_in[5];
    const float* bgv  = (const float*)d_in[6];
    const float* Wo   = (const float*)d_in[7];
    const float* bov  = (const float*)d_in[8];
    const float* Wout = (const float*)d_in[9];
    const float* bout = (const float*)d_in[10];
    float* out = (float*)d_out;

    // ws layout (~68 MB)
    char* p = (char*)d_ws;
    bf16* xb      = (bf16*)p;  p += (size_t)T_STEPS * 131072 * 2;   // 67 MB bf16 x
    bf16* hbuf    = (bf16*)p;  p += (size_t)2 * 131072 * 2;         // h double-buffer (blocked)
    float* logits = (float*)p; p += (size_t)131072 * 4;
    unsigned int* flags = (unsigned int*)p; p += 4096 * 4;          // 4 groups x 64 tiles, 64B apart
    if (ws_size < (size_t)(p - (char*)d_ws)) return;

    init_kernel<<<16384, 256, 0, stream>>>(x, xb, hbuf, flags);
    lstm_persist<<<NWG, 512, 0, stream>>>(xb, Wf, bfv, Wi, biv, Wg, bgv, Wo, bov,
                                          hbuf, flags);
    // t=255 writes hbuf parity 0
    final_gemm_kernel<<<64, 512, 0, stream>>>(hbuf, Wout, bout, logits);
    logsoftmax_kernel<<<128, 256, 0, stream>>>(logits, out);
}